// Round 9
// baseline (118.905 us; speedup 1.0000x reference)
//
#include <hip/hip_runtime.h>
#include <hip/hip_bf16.h>

typedef _Float16 half2v __attribute__((ext_vector_type(2)));
typedef _Float16 half8 __attribute__((ext_vector_type(8)));
typedef __attribute__((ext_vector_type(4))) float floatx4;
typedef __attribute__((ext_vector_type(4))) unsigned int uintx4;

#define GLOBAL_AS __attribute__((address_space(1)))
#define LDS_AS __attribute__((address_space(3)))

// async 16B/lane global->LDS DMA. LDS dest = WAVE-uniform base + lane*16.
__device__ __forceinline__ void async_ld16(const void* g, void* l) {
  __builtin_amdgcn_global_load_lds((const GLOBAL_AS unsigned int*)g,
                                   (LDS_AS unsigned int*)l, 16, 0, 0);
}

__device__ __forceinline__ half2v h2(float v) {
  return (half2v){(_Float16)v, (_Float16)v};
}

// tanh(x0),tanh(x1) -> packed-f16 Legendre P1..P8 for BOTH elements.
// fa0 = low halves (elem0), fa1 = high halves (elem1). ~42 VALU total.
__device__ __forceinline__ void legendre2_f16(float xv0, float xv1,
                                              half8* fa0, half8* fa1) {
  float e0 = __builtin_amdgcn_exp2f(xv0 * 2.885390081777927f); // 2*log2(e)
  float t0 = 1.0f - 2.0f * __builtin_amdgcn_rcpf(e0 + 1.0f);
  float e1 = __builtin_amdgcn_exp2f(xv1 * 2.885390081777927f);
  float t1 = 1.0f - 2.0f * __builtin_amdgcn_rcpf(e1 + 1.0f);
  half2v t;
  { auto tt = __builtin_amdgcn_cvt_pkrtz(t0, t1); __builtin_memcpy(&t, &tt, 4); }
  // P_k = u + c_k*(u - P_{k-2}), u = t*P_{k-1}, c_k=(k-1)/k   (packed, 3 ops/deg)
  half2v p1 = t;
  half2v u2 = t * p1, w2 = u2 - h2(1.0f);  half2v p2 = h2(0.5f)      * w2 + u2;
  half2v u3 = t * p2, w3 = u3 - p1;        half2v p3 = h2(2.0f/3.0f) * w3 + u3;
  half2v u4 = t * p3, w4 = u4 - p2;        half2v p4 = h2(0.75f)     * w4 + u4;
  half2v u5 = t * p4, w5 = u5 - p3;        half2v p5 = h2(0.8f)      * w5 + u5;
  half2v u6 = t * p5, w6 = u6 - p4;        half2v p6 = h2(5.0f/6.0f) * w6 + u6;
  half2v u7 = t * p6, w7 = u7 - p5;        half2v p7 = h2(6.0f/7.0f) * w7 + u7;
  half2v u8 = t * p7, w8 = u8 - p6;        half2v p8 = h2(7.0f/8.0f) * w8 + u8;
  unsigned P[8];
  __builtin_memcpy(&P[0], &p1, 4); __builtin_memcpy(&P[1], &p2, 4);
  __builtin_memcpy(&P[2], &p3, 4); __builtin_memcpy(&P[3], &p4, 4);
  __builtin_memcpy(&P[4], &p5, 4); __builtin_memcpy(&P[5], &p6, 4);
  __builtin_memcpy(&P[6], &p7, 4); __builtin_memcpy(&P[7], &p8, 4);
  union { unsigned u[4]; half8 h; } a0, a1;
#pragma unroll
  for (int j = 0; j < 4; ++j) {
    a0.u[j] = __builtin_amdgcn_perm(P[2*j+1], P[2*j], 0x05040100u); // low halves
    a1.u[j] = __builtin_amdgcn_perm(P[2*j+1], P[2*j], 0x07060302u); // high halves
  }
  *fa0 = a0.h;
  *fa1 = a1.h;
}

// ---- kernel 1: c_basis fp32 -> f16, transposed to ws[i][o][d] (256 KB) ----
__global__ void conv_kernel(const float* __restrict__ cb, _Float16* __restrict__ ws) {
  int t = blockIdx.x * 128 + threadIdx.x;   // 0..16383 = (o,i)
  int o = t >> 8;
  int i = t & 255;
  const floatx4* s = (const floatx4*)(cb + ((size_t)o * 256 + i) * 8);
  floatx4 v0 = s[0], v1 = s[1];
  union { _Float16 h[8]; uintx4 u; } w;
  w.h[0] = (_Float16)v0.x; w.h[1] = (_Float16)v0.y;
  w.h[2] = (_Float16)v0.z; w.h[3] = (_Float16)v0.w;
  w.h[4] = (_Float16)v1.x; w.h[5] = (_Float16)v1.y;
  w.h[6] = (_Float16)v1.z; w.h[7] = (_Float16)v1.w;
  *(uintx4*)(ws + (size_t)i * 512 + o * 8) = w.u;
}

// ---- kernel 2: MB=256, full-K waves, minimal staged bytes ----
// 512 thr = 8 waves, wave rh owns rows rb+rh*32..+31, FULL K=256 (no kh
// split, no reduction epilogue). Grid 256 -> 1 block/CU, LDS 96 KB,
// 8 waves/CU (2/SIMD — occupancy proven irrelevant R0-R8).
// 16 steps; step stages 16 B i-rows (slot t=0..15 -> i = step*16 + t; wave
// stages t = rh*2, rh*2+1) + 16 KB x (256 rows x 16 cols). Every staged B
// slot is read by ALL 8 waves (8x LDS reuse); B global traffic 64 MB total.
// R8-verified discipline: triple-buffer depth-2; WAR barrier -> stage(ch+2)
// [4 DMA/wave] -> vmcnt(8) [drains stage(ch); leaves ch+1,ch+2 in flight]
// -> RAW barrier -> compute. vmcnt(4) at step 14, vmcnt(0) at 15.
// x LDS: 16B units, unit u: row = u>>2, stored piece p' = u&3, global piece
// p = p' ^ ((row>>1)&3) (both-sides XOR swizzle; read = 2-way aliasing,
// free). Compute, per ks=0..3: i = step*16 + ks*4 + q; A from legendre of
// x[row0(+16)][i] (stored piece ks^sw, sw=(row0>>1)&3); B slot ks*4+q at
// fragment q-invariant addr slot*512 + m*8 (+nt*128) — same per-q i pairing
// invariant as all passing rounds. Epilogue: direct store + bias.
#define NSTEP 16

__global__ __launch_bounds__(512, 2) void kan_kernel(
    const float* __restrict__ x, const _Float16* __restrict__ ws,
    const float* __restrict__ bias, float* __restrict__ y) {
  __shared__ __align__(16) _Float16 bt[3][8192]; // 16 slots x 512h, 3 bufs: 48 KB
  __shared__ __align__(16) float xs[3][4096];    // 256 rows x 16 cols, 3 bufs: 48 KB

  const int tid  = threadIdx.x;
  const int wid  = tid >> 6;     // 0..7 = rh (row-eighth, 32 rows)
  const int lane = tid & 63;
  const int m    = lane & 15;
  const int q    = lane >> 4;
  const int rb   = blockIdx.x * 256;

  floatx4 acc[2][4];
#pragma unroll
  for (int a = 0; a < 2; ++a)
#pragma unroll
    for (int nt = 0; nt < 4; ++nt) acc[a][nt] = (floatx4){0.f, 0.f, 0.f, 0.f};

  // B DMA src: slots t = wid*2, wid*2+1; i-row i = step*16 + t (1 KB each)
  const _Float16* bsrc0 = ws + (size_t)(wid * 2 + 0) * 512 + lane * 8;
  const _Float16* bsrc1 = ws + (size_t)(wid * 2 + 1) * 512 + lane * 8;

  // x DMA src: 2 units/lane: u = wid*128 + k*64 + lane; row = u>>2,
  // stored piece p' = u&3, global piece p = p' ^ ((row>>1)&3);
  // col = step*16 + p*4  (advance +16 floats per step)
  const float* xsrc0;
  const float* xsrc1;
  {
    int u0 = wid * 128 + lane;
    int r0_ = u0 >> 2, p0 = (u0 & 3) ^ ((r0_ >> 1) & 3);
    xsrc0 = x + (size_t)(rb + r0_) * 256 + p0 * 4;
    int u1 = wid * 128 + 64 + lane;
    int r1_ = u1 >> 2, p1 = (u1 & 3) ^ ((r1_ >> 1) & 3);
    xsrc1 = x + (size_t)(rb + r1_) * 256 + p1 * 4;
  }

  // 4 DMAs per wave per stage call: 2 B i-rows + 2 x unit-blocks (1 KB each)
  auto stage = [&](int b) {
    async_ld16(bsrc0, &bt[b][(wid * 2 + 0) * 512]);
    async_ld16(bsrc1, &bt[b][(wid * 2 + 1) * 512]);
    bsrc0 += 8192; bsrc1 += 8192;                 // +16 i-rows
    async_ld16(xsrc0, &xs[b][wid * 512]);
    async_ld16(xsrc1, &xs[b][wid * 512 + 256]);
    xsrc0 += 16; xsrc1 += 16;                     // +16 cols
  };

  stage(0);          // step 0 -> buf 0
  stage(1);          // step 1 -> buf 1   (8 DMAs in flight)

  const int row0 = wid * 32 + m;         // row-stream 0 (stream 1 = +16)
  const int sw   = (m >> 1) & 3;         // x swizzle key ((row0>>1)&3)

  auto compute = [&](int buf) {
#pragma unroll
    for (int ks = 0; ks < 4; ++ks) {
      const int xi = row0 * 16 + ((ks ^ sw) << 2) + q;
      float xv0 = xs[buf][xi];
      float xv1 = xs[buf][xi + 256];     // row0+16 -> +16*16 floats
      half8 f0, f1;
      legendre2_f16(xv0, xv1, &f0, &f1);
      const _Float16* bp = &bt[buf][(ks * 4 + q) * 512 + m * 8];
      half8 fb0 = *(const half8*)(bp + 0);
      half8 fb1 = *(const half8*)(bp + 128);
      half8 fb2 = *(const half8*)(bp + 256);
      half8 fb3 = *(const half8*)(bp + 384);
      __builtin_amdgcn_s_setprio(1);
      acc[0][0] = __builtin_amdgcn_mfma_f32_16x16x32_f16(f0, fb0, acc[0][0], 0, 0, 0);
      acc[1][0] = __builtin_amdgcn_mfma_f32_16x16x32_f16(f1, fb0, acc[1][0], 0, 0, 0);
      acc[0][1] = __builtin_amdgcn_mfma_f32_16x16x32_f16(f0, fb1, acc[0][1], 0, 0, 0);
      acc[1][1] = __builtin_amdgcn_mfma_f32_16x16x32_f16(f1, fb1, acc[1][1], 0, 0, 0);
      acc[0][2] = __builtin_amdgcn_mfma_f32_16x16x32_f16(f0, fb2, acc[0][2], 0, 0, 0);
      acc[1][2] = __builtin_amdgcn_mfma_f32_16x16x32_f16(f1, fb2, acc[1][2], 0, 0, 0);
      acc[0][3] = __builtin_amdgcn_mfma_f32_16x16x32_f16(f0, fb3, acc[0][3], 0, 0, 0);
      acc[1][3] = __builtin_amdgcn_mfma_f32_16x16x32_f16(f1, fb3, acc[1][3], 0, 0, 0);
      __builtin_amdgcn_s_setprio(0);
    }
  };

  // Step ch: WAR barrier (buf (ch+2)%3 last read at step ch-1) ->
  // stage(ch+2) -> vmcnt(N) [drains stage(ch)] -> RAW barrier -> compute.
#define STEP(ch, N)                                                            \
  {                                                                            \
    asm volatile("s_barrier" ::: "memory");                                    \
    if constexpr ((ch) + 2 < NSTEP) stage(((ch) + 2) % 3);                     \
    asm volatile("s_waitcnt vmcnt(" #N ")" ::: "memory");                      \
    asm volatile("s_barrier" ::: "memory");                                    \
    compute((ch) % 3);                                                         \
  }

  STEP(0, 8)  STEP(1, 8)  STEP(2, 8)  STEP(3, 8)
  STEP(4, 8)  STEP(5, 8)  STEP(6, 8)  STEP(7, 8)
  STEP(8, 8)  STEP(9, 8)  STEP(10, 8) STEP(11, 8)
  STEP(12, 8) STEP(13, 8) STEP(14, 4) STEP(15, 0)
#undef STEP

  // ---- epilogue: direct store + bias (no reduction — full K per wave) ----
  float bv[4];
#pragma unroll
  for (int nt = 0; nt < 4; ++nt) bv[nt] = bias[nt * 16 + m];
#pragma unroll
  for (int a = 0; a < 2; ++a) {
    int gr0 = rb + wid * 32 + a * 16 + q * 4;
#pragma unroll
    for (int nt = 0; nt < 4; ++nt) {
#pragma unroll
      for (int r = 0; r < 4; ++r) {
        y[(size_t)(gr0 + r) * 64 + nt * 16 + m] = acc[a][nt][r] + bv[nt];
      }
    }
  }
}

extern "C" void kernel_launch(void* const* d_in, const int* in_sizes, int n_in,
                              void* d_out, int out_size, void* d_ws, size_t ws_size,
                              hipStream_t stream) {
  const float* x    = (const float*)d_in[0];
  const float* cb   = (const float*)d_in[1];
  const float* bias = (const float*)d_in[2];
  float* y = (float*)d_out;
  _Float16* ws = (_Float16*)d_ws;
  int batch = in_sizes[0] / 256;  // 65536
  hipLaunchKernelGGL(conv_kernel, dim3(128), dim3(128), 0, stream, cb, ws);
  hipLaunchKernelGGL(kan_kernel, dim3(batch / 256), dim3(512), 0, stream, x, ws, bias, y);
}